// Round 1
// baseline (3558.936 us; speedup 1.0000x reference)
//
#include <hip/hip_runtime.h>
#include <math.h>

#define NN 50000
#define HH 384
#define KKC 16
#define PER 6250
#define EE 1600000
#define NKE 800000   // N*K

// ---------------- ws layout (bytes) ----------------
// [0, 12.8M)            nbrs  int[N*64]        } reused after matching as
// [12.8M, 25.6M)        wts   float[N*64]      } adj int[N*128]
// [25.6M..]             cnt2, adjcnt, cluster, mate, newid, cmap, repof, nc
// [27.0M+256, +76.8M)   aggr  float[N*384]
#define OFF_NBRS   0UL
#define OFF_WTS    12800000UL
#define OFF_ADJ    0UL
#define OFF_CNT2   25600000UL
#define OFF_ADJC   25800000UL
#define OFF_CLUS   26000000UL
#define OFF_MATE   26200000UL
#define OFF_NEWID  26400000UL
#define OFF_CMAP   26600000UL
#define OFF_REPOF  26800000UL
#define OFF_NC     27000000UL
#define OFF_AGGR   27000256UL

// K0: zero counters
__global__ void k0_init(int* cnt2, int* adjcnt) {
    int i = blockIdx.x * blockDim.x + threadIdx.x;
    if (i < NN) { cnt2[i] = 0; adjcnt[i] = 0; }
}

// K1: block-1 neighbors (the 16 out-edges, in storage order) + init rest
__global__ void k1_build(const int* __restrict__ ei, const float* __restrict__ ew,
                         int* __restrict__ nbrs, float* __restrict__ wts) {
    int id = blockIdx.x * blockDim.x + threadIdx.x;  // N*64
    if (id >= NN * 64) return;
    int slot = id & 63;
    int u = id >> 6;
    if (slot < KKC) {
        int e = u * KKC + slot;
        nbrs[id] = ei[EE + e];   // row1[e] = dst_orig
        wts[id]  = ew[e];
    } else {
        nbrs[id] = -1;
        wts[id]  = -INFINITY;
    }
}

// K2: scatter block-2 in-edges (store edge index i temporarily), unordered
__global__ void k2_scatter(const int* __restrict__ ei, int* __restrict__ cnt2,
                           int* __restrict__ nbrs) {
    int i = blockIdx.x * blockDim.x + threadIdx.x;   // NK
    if (i >= NKE) return;
    int u = ei[EE + i];                 // dst_orig[i] -> source node of reversed edge
    int slot = atomicAdd(&cnt2[u], 1);
    if (slot < 48) nbrs[u * 64 + 16 + slot] = i;
}

// K3: per-node stable rank by edge index -> final neighbor/weight slots
__global__ __launch_bounds__(256) void k3_rank(const int* __restrict__ cnt2,
                                               const float* __restrict__ ew,
                                               int* __restrict__ nbrs,
                                               float* __restrict__ wts) {
    int gid = blockIdx.x * blockDim.x + threadIdx.x;
    int u = gid >> 6;
    int lane = gid & 63;
    if (u >= NN) return;
    int cnt = cnt2[u]; if (cnt > 48) cnt = 48;
    int myi = (lane < cnt) ? nbrs[u * 64 + 16 + lane] : 0x7FFFFFFF;
    int rank = 0;
    for (int m = 0; m < cnt; ++m) {
        int ov = __shfl(myi, m, 64);
        if (lane < cnt && m != lane && ov < myi) rank++;
    }
    if (lane < cnt) {
        nbrs[u * 64 + 16 + rank] = myi >> 4;        // /16 = src_orig = neighbor
        wts [u * 64 + 16 + rank] = ew[NKE + myi];
    }
}

// K4: 8 independent sequential greedy matchings (one wave per graph)
__device__ __forceinline__ void graclus_step(int u, int cnb, float cwt, int base, int lane,
                                             unsigned int* mbits, int* clus, int* mt) {
    unsigned um = (mbits[u >> 5] >> (u & 31)) & 1u;
    if (!um) {
        int nl = cnb - base;
        bool pre = (cnb >= 0) && (nl != u);
        int safe = pre ? nl : 0;
        bool cand = pre && !((mbits[safe >> 5] >> (safe & 31)) & 1u);
        unsigned long long bal = __ballot(cand);
        if (bal) {
            float wv = cand ? cwt : -INFINITY;
            int bslot = lane, bv = nl;
            #pragma unroll
            for (int off = 32; off >= 1; off >>= 1) {
                float ow = __shfl_xor(wv, off, 64);
                int   os = __shfl_xor(bslot, off, 64);
                int   ov = __shfl_xor(bv, off, 64);
                if (ow > wv || (ow == wv && os < bslot)) { wv = ow; bslot = os; bv = ov; }
            }
            if (lane == 0) {
                int v = bv;
                clus[v] = u; mt[u] = v; mt[v] = u;
                mbits[u >> 5] |= (1u << (u & 31));
                mbits[v >> 5] |= (1u << (v & 31));
            }
        } else {
            if (lane == 0) mbits[u >> 5] |= (1u << (u & 31));
        }
    }
    __syncthreads();
}

__global__ __launch_bounds__(64) void k4_graclus(const int* __restrict__ nbrs,
                                                 const float* __restrict__ wts,
                                                 int* __restrict__ cluster,
                                                 int* __restrict__ mate) {
    __shared__ unsigned int mbits[PER / 32 + 1];
    __shared__ int clus[PER];
    __shared__ int mt[PER];
    const int base = blockIdx.x * PER;
    const int lane = threadIdx.x;
    for (int i = lane; i < PER / 32 + 1; i += 64) mbits[i] = 0u;
    for (int i = lane; i < PER; i += 64) { clus[i] = i; mt[i] = -1; }
    __syncthreads();
    const int*   nrow = nbrs + (size_t)base * 64;
    const float* wrow = wts  + (size_t)base * 64;
    auto ldrow = [&](int r, int& nb, float& wt) {
        int rr = r < PER ? r : PER - 1;
        nb = nrow[(size_t)rr * 64 + lane];
        wt = wrow[(size_t)rr * 64 + lane];
    };
    int nb0,nb1,nb2,nb3, pb0,pb1,pb2,pb3;
    float wt0,wt1,wt2,wt3, pw0,pw1,pw2,pw3;
    ldrow(0,nb0,wt0); ldrow(1,nb1,wt1); ldrow(2,nb2,wt2); ldrow(3,nb3,wt3);
    ldrow(4,pb0,pw0); ldrow(5,pb1,pw1); ldrow(6,pb2,pw2); ldrow(7,pb3,pw3);
    for (int u0 = 0; u0 < PER; u0 += 4) {
        graclus_step(u0 + 0, nb0, wt0, base, lane, mbits, clus, mt);
        if (u0 + 1 < PER) graclus_step(u0 + 1, nb1, wt1, base, lane, mbits, clus, mt);
        if (u0 + 2 < PER) graclus_step(u0 + 2, nb2, wt2, base, lane, mbits, clus, mt);
        if (u0 + 3 < PER) graclus_step(u0 + 3, nb3, wt3, base, lane, mbits, clus, mt);
        nb0=pb0; wt0=pw0; nb1=pb1; wt1=pw1; nb2=pb2; wt2=pw2; nb3=pb3; wt3=pw3;
        ldrow(u0+8,  pb0, pw0); ldrow(u0+9,  pb1, pw1);
        ldrow(u0+10, pb2, pw2); ldrow(u0+11, pb3, pw3);
    }
    for (int i = lane; i < PER; i += 64) {
        cluster[base + i] = base + clus[i];
        int m = mt[i];
        mate[base + i] = (m < 0) ? -1 : base + m;
    }
}

// K5: single-block inclusive scan of is_rep -> new_id, nc
__global__ __launch_bounds__(1024) void k5_scan(const int* __restrict__ cluster,
                                                int* __restrict__ newid,
                                                int* __restrict__ ncp) {
    __shared__ int wsum[16];
    __shared__ int carry;
    const int tid = threadIdx.x;
    const int lane = tid & 63;
    const int wid = tid >> 6;
    if (tid == 0) carry = 0;
    __syncthreads();
    for (int bse = 0; bse < NN; bse += 1024) {
        int u = bse + tid;
        int v = (u < NN && cluster[u] == u) ? 1 : 0;
        int s = v;
        #pragma unroll
        for (int off = 1; off < 64; off <<= 1) {
            int t = __shfl_up(s, off, 64);
            if (lane >= off) s += t;
        }
        if (lane == 63) wsum[wid] = s;
        __syncthreads();
        if (wid == 0) {
            int w2 = (lane < 16) ? wsum[lane] : 0;
            #pragma unroll
            for (int off = 1; off < 16; off <<= 1) {
                int t = __shfl_up(w2, off, 64);
                if (lane >= off) w2 += t;
            }
            if (lane < 16) wsum[lane] = w2;
        }
        __syncthreads();
        int wpre = (wid > 0) ? wsum[wid - 1] : 0;
        int carryv = carry;
        if (u < NN) newid[u] = carryv + wpre + s - 1;
        int total = wsum[15];
        __syncthreads();
        if (tid == 0) carry = carryv + total;
        __syncthreads();
    }
    if (tid == 0) *ncp = carry;
}

// K6: cluster id map + representative lookup
__global__ void k6_relabel(const int* __restrict__ cluster, const int* __restrict__ newid,
                           int* __restrict__ cmap, int* __restrict__ repof) {
    int u = blockIdx.x * blockDim.x + threadIdx.x;
    if (u >= NN) return;
    int cl = cluster[u];
    int cid = newid[cl];
    cmap[u] = cid;
    if (cl == u) repof[cid] = u;
}

// K7: max-pool features into d_out's [N,H] region + pooled batch vector
__global__ __launch_bounds__(128) void k7_pool(const float* __restrict__ h,
                                               const int* __restrict__ repof,
                                               const int* __restrict__ mate,
                                               const int* __restrict__ batch,
                                               const int* __restrict__ ncp,
                                               float* __restrict__ xout,
                                               float* __restrict__ bpool) {
    int cid = blockIdx.x;
    int tid = threadIdx.x;
    int nc = *ncp;
    if (cid >= nc) {
        #pragma unroll
        for (int q = 0; q < 3; ++q) xout[(size_t)cid * HH + tid + q * 128] = 0.f;
        if (tid == 0) bpool[cid] = 0.f;
        return;
    }
    int u = repof[cid];
    int v = mate[u];
    const float* hu = h + (size_t)u * HH;
    const float* hv = h + (size_t)(v >= 0 ? v : u) * HH;
    #pragma unroll
    for (int q = 0; q < 3; ++q) {
        int j = tid + q * 128;
        float a = hu[j];
        if (v >= 0) a = fmaxf(a, hv[j]);
        xout[(size_t)cid * HH + j] = a;
    }
    if (tid == 0) bpool[cid] = (float)batch[u];
}

// K8: per-destination-cluster candidate source lists (with duplicates)
__global__ void k8_adj(const int* __restrict__ ei, const int* __restrict__ cmap,
                       int* __restrict__ adjcnt, int* __restrict__ adj) {
    int g = blockIdx.x * blockDim.x + threadIdx.x;
    if (g >= EE) return;
    int cs = cmap[ei[g]];
    int cd = cmap[ei[EE + g]];
    if (cs == cd) return;
    int slot = atomicAdd(&adjcnt[cd], 1);
    if (slot < 128) adj[(size_t)cd * 128 + slot] = cs;
}

// K9: dedupe + sum pooled rows -> aggr
__global__ __launch_bounds__(128) void k9_aggr(const int* __restrict__ adjcnt,
                                               const int* __restrict__ adj,
                                               const float* __restrict__ x,
                                               const int* __restrict__ ncp,
                                               float* __restrict__ aggr) {
    int cid = blockIdx.x;
    int tid = threadIdx.x;
    if (cid >= *ncp) return;
    int cnt = adjcnt[cid]; if (cnt > 128) cnt = 128;
    __shared__ int vals[128];
    __shared__ int keep[128];
    if (tid < cnt) vals[tid] = adj[(size_t)cid * 128 + tid];
    __syncthreads();
    if (tid < cnt) {
        int v = vals[tid]; int k = 1;
        for (int m = 0; m < tid; ++m) if (vals[m] == v) { k = 0; break; }
        keep[tid] = k;
    }
    __syncthreads();
    float a0 = 0.f, a1 = 0.f, a2 = 0.f;
    for (int e = 0; e < cnt; ++e) {
        if (keep[e]) {
            const float* xr = x + (size_t)vals[e] * HH;
            a0 += xr[tid]; a1 += xr[tid + 128]; a2 += xr[tid + 256];
        }
    }
    aggr[(size_t)cid * HH + tid]       = a0;
    aggr[(size_t)cid * HH + tid + 128] = a1;
    aggr[(size_t)cid * HH + tid + 256] = a2;
}

// K10: out = relu([aggr | max(h_u,h_v)] @ [Wrel|Wroot]^T + b_rel), rows < nc only.
// Never reads d_out (x recomputed from h) -> no aliasing hazard.
__global__ __launch_bounds__(256) void k10_gemm(const float* __restrict__ aggr,
                                                const float* __restrict__ h,
                                                const int* __restrict__ repof,
                                                const int* __restrict__ mate,
                                                const float* __restrict__ Wrel,
                                                const float* __restrict__ Wroot,
                                                const float* __restrict__ brel,
                                                float* __restrict__ out,
                                                const int* __restrict__ ncp) {
    const int nc = *ncp;
    const int row0 = blockIdx.x * 64;
    const int col0 = blockIdx.y * 64;
    if (row0 >= nc) return;
    __shared__ float As[32][68];
    __shared__ float Ws[32][68];
    __shared__ int us[64], vs[64];
    const int tid = threadIdx.x;
    if (tid < 64) {
        int r = row0 + tid;
        int u = 0, v = -1;
        if (r < nc) { u = repof[r]; v = mate[u]; }
        us[tid] = u; vs[tid] = v;
    }
    __syncthreads();
    float acc[4][4] = {};
    const int ty = tid >> 4, tx = tid & 15;
    for (int kt = 0; kt < 2 * HH; kt += 32) {
        #pragma unroll
        for (int q = 0; q < 2; ++q) {
            int idx = tid + q * 256;
            int r   = idx >> 3;
            int kq  = (idx & 7) << 2;
            int k   = kt + kq;
            int grow = row0 + r;
            bool rv = (grow < nc);
            float4 val;
            if (k < HH) {
                val = *(const float4*)(aggr + (size_t)(rv ? grow : 0) * HH + k);
            } else {
                int kk = k - HH;
                int u = us[r], v = vs[r];
                float4 a = *(const float4*)(h + (size_t)u * HH + kk);
                if (v >= 0) {
                    float4 b = *(const float4*)(h + (size_t)v * HH + kk);
                    a.x = fmaxf(a.x, b.x); a.y = fmaxf(a.y, b.y);
                    a.z = fmaxf(a.z, b.z); a.w = fmaxf(a.w, b.w);
                }
                val = a;
            }
            if (!rv) val = make_float4(0.f, 0.f, 0.f, 0.f);
            As[kq + 0][r] = val.x; As[kq + 1][r] = val.y;
            As[kq + 2][r] = val.z; As[kq + 3][r] = val.w;
        }
        {
            const float* Wsrc = (kt < HH) ? Wrel : Wroot;
            int kk0 = (kt < HH) ? kt : kt - HH;
            #pragma unroll
            for (int q = 0; q < 2; ++q) {
                int idx = tid + q * 256;
                int j   = idx >> 3;
                int kq  = (idx & 7) << 2;
                float4 w = *(const float4*)(Wsrc + (size_t)(col0 + j) * HH + kk0 + kq);
                Ws[kq + 0][j] = w.x; Ws[kq + 1][j] = w.y;
                Ws[kq + 2][j] = w.z; Ws[kq + 3][j] = w.w;
            }
        }
        __syncthreads();
        #pragma unroll
        for (int k = 0; k < 32; ++k) {
            float a[4], w[4];
            #pragma unroll
            for (int i = 0; i < 4; ++i) a[i] = As[k][ty * 4 + i];
            #pragma unroll
            for (int n = 0; n < 4; ++n) w[n] = Ws[k][tx * 4 + n];
            #pragma unroll
            for (int i = 0; i < 4; ++i)
                #pragma unroll
                for (int n = 0; n < 4; ++n)
                    acc[i][n] += a[i] * w[n];
        }
        __syncthreads();
    }
    #pragma unroll
    for (int i = 0; i < 4; ++i) {
        int r = row0 + ty * 4 + i;
        if (r >= nc) continue;
        #pragma unroll
        for (int n = 0; n < 4; ++n) {
            int j = col0 + tx * 4 + n;
            float v = acc[i][n] + brel[j];
            out[(size_t)r * HH + j] = v > 0.f ? v : 0.f;
        }
    }
}

extern "C" void kernel_launch(void* const* d_in, const int* in_sizes, int n_in,
                              void* d_out, int out_size, void* d_ws, size_t ws_size,
                              hipStream_t stream) {
    const float* h     = (const float*)d_in[0];
    const int*   ei    = (const int*)d_in[1];
    const float* ew    = (const float*)d_in[2];
    const int*   batch = (const int*)d_in[3];
    const float* Wrel  = (const float*)d_in[4];
    const float* brel  = (const float*)d_in[5];
    const float* Wroot = (const float*)d_in[6];
    float* out = (float*)d_out;

    unsigned char* w8 = (unsigned char*)d_ws;
    int*   nbrs   = (int*)(w8 + OFF_NBRS);
    float* wts    = (float*)(w8 + OFF_WTS);
    int*   adj    = (int*)(w8 + OFF_ADJ);     // reuses nbrs+wts region after K4
    int*   cnt2   = (int*)(w8 + OFF_CNT2);
    int*   adjcnt = (int*)(w8 + OFF_ADJC);
    int*   clus   = (int*)(w8 + OFF_CLUS);
    int*   mate   = (int*)(w8 + OFF_MATE);
    int*   newid  = (int*)(w8 + OFF_NEWID);
    int*   cmap   = (int*)(w8 + OFF_CMAP);
    int*   repof  = (int*)(w8 + OFF_REPOF);
    int*   ncp    = (int*)(w8 + OFF_NC);
    float* aggr   = (float*)(w8 + OFF_AGGR);

    float* xout  = out;            // [N,H] region of d_out doubles as pooled-x storage
    float* bpool = out + (size_t)NN * HH;

    hipLaunchKernelGGL(k0_init,    dim3((NN + 255) / 256), dim3(256), 0, stream, cnt2, adjcnt);
    hipLaunchKernelGGL(k1_build,   dim3((NN * 64 + 255) / 256), dim3(256), 0, stream, ei, ew, nbrs, wts);
    hipLaunchKernelGGL(k2_scatter, dim3((NKE + 255) / 256), dim3(256), 0, stream, ei, cnt2, nbrs);
    hipLaunchKernelGGL(k3_rank,    dim3((NN * 64 + 255) / 256), dim3(256), 0, stream, cnt2, ew, nbrs, wts);
    hipLaunchKernelGGL(k4_graclus, dim3(8), dim3(64), 0, stream, nbrs, wts, clus, mate);
    hipLaunchKernelGGL(k5_scan,    dim3(1), dim3(1024), 0, stream, clus, newid, ncp);
    hipLaunchKernelGGL(k6_relabel, dim3((NN + 255) / 256), dim3(256), 0, stream, clus, newid, cmap, repof);
    hipLaunchKernelGGL(k7_pool,    dim3(NN), dim3(128), 0, stream, h, repof, mate, batch, ncp, xout, bpool);
    hipLaunchKernelGGL(k8_adj,     dim3((EE + 255) / 256), dim3(256), 0, stream, ei, cmap, adjcnt, adj);
    hipLaunchKernelGGL(k9_aggr,    dim3(NN), dim3(128), 0, stream, adjcnt, adj, xout, ncp, aggr);
    hipLaunchKernelGGL(k10_gemm,   dim3((NN + 63) / 64, HH / 64), dim3(256), 0, stream,
                       aggr, h, repof, mate, Wrel, Wroot, brel, out, ncp);
}

// Round 2
// 2304.489 us; speedup vs baseline: 1.5443x; 1.5443x over previous
//
#include <hip/hip_runtime.h>
#include <math.h>

#define NN 50000
#define HH 384
#define KKC 16
#define PER 6250
#define EE 1600000
#define NKE 800000   // N*K

// ---------------- ws layout (bytes) ----------------
#define OFF_NBRS   0UL
#define OFF_WTS    12800000UL
#define OFF_ADJ    0UL
#define OFF_CNT2   25600000UL
#define OFF_ADJC   25800000UL
#define OFF_CLUS   26000000UL
#define OFF_MATE   26200000UL
#define OFF_NEWID  26400000UL
#define OFF_CMAP   26600000UL
#define OFF_REPOF  26800000UL
#define OFF_NC     27000000UL
#define OFF_AGGR   27000256UL

// K0: zero counters
__global__ void k0_init(int* cnt2, int* adjcnt) {
    int i = blockIdx.x * blockDim.x + threadIdx.x;
    if (i < NN) { cnt2[i] = 0; adjcnt[i] = 0; }
}

// K1: block-1 neighbors (the 16 out-edges, in storage order) + init rest
__global__ void k1_build(const int* __restrict__ ei, const float* __restrict__ ew,
                         int* __restrict__ nbrs, float* __restrict__ wts) {
    int id = blockIdx.x * blockDim.x + threadIdx.x;  // N*64
    if (id >= NN * 64) return;
    int slot = id & 63;
    int u = id >> 6;
    if (slot < KKC) {
        int e = u * KKC + slot;
        nbrs[id] = ei[EE + e];   // row1[e] = dst_orig
        wts[id]  = ew[e];
    } else {
        nbrs[id] = -1;
        wts[id]  = -INFINITY;
    }
}

// K2: scatter block-2 in-edges (store edge index i temporarily), unordered
__global__ void k2_scatter(const int* __restrict__ ei, int* __restrict__ cnt2,
                           int* __restrict__ nbrs) {
    int i = blockIdx.x * blockDim.x + threadIdx.x;   // NK
    if (i >= NKE) return;
    int u = ei[EE + i];
    int slot = atomicAdd(&cnt2[u], 1);
    if (slot < 48) nbrs[u * 64 + 16 + slot] = i;
}

// K3: per-node stable rank by edge index -> final neighbor/weight slots
__global__ __launch_bounds__(256) void k3_rank(const int* __restrict__ cnt2,
                                               const float* __restrict__ ew,
                                               int* __restrict__ nbrs,
                                               float* __restrict__ wts) {
    int gid = blockIdx.x * blockDim.x + threadIdx.x;
    int u = gid >> 6;
    int lane = gid & 63;
    if (u >= NN) return;
    int cnt = cnt2[u]; if (cnt > 48) cnt = 48;
    int myi = (lane < cnt) ? nbrs[u * 64 + 16 + lane] : 0x7FFFFFFF;
    int rank = 0;
    for (int m = 0; m < cnt; ++m) {
        int ov = __shfl(myi, m, 64);
        if (lane < cnt && m != lane && ov < myi) rank++;
    }
    if (lane < cnt) {
        nbrs[u * 64 + 16 + rank] = myi >> 4;        // /16 = src_orig = neighbor
        wts [u * 64 + 16 + rank] = ew[NKE + myi];
    }
}

// ---------------- K4: fast sequential greedy matching ----------------
// Per step critical chain: register mask ops -> 6-stage DPP f32 max-reduce ->
// readlane/ballot/ctz. Matched-bitmap gathers are issued 4 steps early and
// corrected against the last 3 grabs (v1,v2,v3) using the invariant that every
// node with index < u is already matched by step u.
#define DPPMAX(x, ctrl) fmaxf((x), __int_as_float(__builtin_amdgcn_update_dpp( \
        (int)0xFF800000, __float_as_int(x), (ctrl), 0xf, 0xf, false)))

__device__ __forceinline__ void gstep(int u, int nl, float wt, unsigned gw, unsigned hw,
                                      int lane, unsigned* mbits, int* clus, int* mt,
                                      int& v1, int& v2, int& v3) {
    // u already matched? (stale broadcast word + recent-grab correction; uniform)
    bool um = (((hw >> (u & 31)) & 1u) != 0u) || (u == v1) || (u == v2) || (u == v3);
    int vnew = -1;
    if (!um) {
        // candidates: strictly later unmatched neighbors (all nl<u are matched)
        bool cand = (nl > u) && !((gw >> (nl & 31)) & 1u)
                    && (nl != v1) && (nl != v2) && (nl != v3);
        unsigned long long bal = __ballot(cand);
        if (bal) {
            float wv = cand ? wt : -INFINITY;
            float m = wv;
            m = DPPMAX(m, 0x111);   // row_shr:1
            m = DPPMAX(m, 0x112);   // row_shr:2
            m = DPPMAX(m, 0x114);   // row_shr:4
            m = DPPMAX(m, 0x118);   // row_shr:8
            m = DPPMAX(m, 0x142);   // row_bcast:15
            m = DPPMAX(m, 0x143);   // row_bcast:31  -> lane 63 holds wave max
            float wmax = __int_as_float(__builtin_amdgcn_readlane(__float_as_int(m), 63));
            unsigned long long em = __ballot(cand && (wv == wmax));
            int j = (int)__builtin_ctzll(em);          // lowest slot on ties = jnp.argmax
            int vl = __builtin_amdgcn_readlane(nl, j);
            if (lane == 0) {
                atomicOr(&mbits[u  >> 5], 1u << (u  & 31));
                atomicOr(&mbits[vl >> 5], 1u << (vl & 31));
                mt[u] = vl; mt[vl] = u; clus[vl] = u;
            }
            vnew = vl;
        } else {
            if (lane == 0) atomicOr(&mbits[u >> 5], 1u << (u & 31));
        }
    }
    v3 = v2; v2 = v1; v1 = vnew;
}

__global__ __launch_bounds__(64) void k4_graclus(const int* __restrict__ nbrs,
                                                 const float* __restrict__ wts,
                                                 int* __restrict__ cluster,
                                                 int* __restrict__ mate) {
    __shared__ unsigned mbits[PER / 32 + 1];
    __shared__ int clus[PER];
    __shared__ int mt[PER];
    const int base = blockIdx.x * PER;
    const int lane = threadIdx.x;
    for (int i = lane; i < PER / 32 + 1; i += 64) mbits[i] = 0u;
    for (int i = lane; i < PER; i += 64) { clus[i] = i; mt[i] = -1; }
    __syncthreads();

    const int*   nrow = nbrs + (size_t)base * 64;
    const float* wrow = wts  + (size_t)base * 64;
    auto ldrow = [&](int r, int& nl, float& wt) {
        int rr = r < PER ? r : PER - 1;
        nl = nrow[(size_t)rr * 64 + lane] - base;   // invalid (-1) -> negative local
        wt = wrow[(size_t)rr * 64 + lane];
    };

    // 12-deep global row prefetch: n* (current 4), pb* (next 4), pc* (next+4)
    int   n0,n1,n2,n3, pb0,pb1,pb2,pb3, pc0,pc1,pc2,pc3;
    float w0,w1,w2,w3, qb0,qb1,qb2,qb3, qc0,qc1,qc2,qc3;
    ldrow(0,n0,w0);   ldrow(1,n1,w1);   ldrow(2,n2,w2);   ldrow(3,n3,w3);
    ldrow(4,pb0,qb0); ldrow(5,pb1,qb1); ldrow(6,pb2,qb2); ldrow(7,pb3,qb3);
    ldrow(8,pc0,qc0); ldrow(9,pc1,qc1); ldrow(10,pc2,qc2); ldrow(11,pc3,qc3);

    // bitmap-gather pipeline for current 4 steps (state before step 0 = empty)
    unsigned g0 = 0u, g1 = 0u, g2 = 0u, g3 = 0u;   // per-lane word of matched[nl]
    unsigned h0 = 0u, h1 = 0u, h2 = 0u, h3 = 0u;   // broadcast word of matched[u]
    int v1 = -1, v2 = -1, v3 = -1;                 // last 3 grabs

    for (int u0 = 0; u0 < PER; u0 += 4) {
        gstep(u0 + 0, n0, w0, g0, h0, lane, mbits, clus, mt, v1, v2, v3);
        if (u0 + 1 < PER) gstep(u0 + 1, n1, w1, g1, h1, lane, mbits, clus, mt, v1, v2, v3);
        if (u0 + 2 < PER) gstep(u0 + 2, n2, w2, g2, h2, lane, mbits, clus, mt, v1, v2, v3);
        if (u0 + 3 < PER) gstep(u0 + 3, n3, w3, g3, h3, lane, mbits, clus, mt, v1, v2, v3);
        // pin program order: this group's ds_or updates issue before next gathers
        __builtin_amdgcn_sched_barrier(0);
        // issue bitmap gathers for steps u0+4..u0+7 (consumed next group; any
        // staleness <= 3 steps is covered by v1..v3 + the nl>u invariant)
        g0 = mbits[(pb0 < 0 ? 0 : pb0) >> 5];  h0 = mbits[(u0 + 4) >> 5];
        g1 = mbits[(pb1 < 0 ? 0 : pb1) >> 5];  h1 = mbits[(u0 + 5) >> 5];
        g2 = mbits[(pb2 < 0 ? 0 : pb2) >> 5];  h2 = mbits[(u0 + 6) >> 5];
        g3 = mbits[(pb3 < 0 ? 0 : pb3) >> 5];  h3 = mbits[(u0 + 7) >> 5];
        // rotate row banks, prefetch rows u0+12..u0+15
        n0=pb0; w0=qb0; n1=pb1; w1=qb1; n2=pb2; w2=qb2; n3=pb3; w3=qb3;
        pb0=pc0; qb0=qc0; pb1=pc1; qb1=qc1; pb2=pc2; qb2=qc2; pb3=pc3; qb3=qc3;
        ldrow(u0+12, pc0, qc0); ldrow(u0+13, pc1, qc1);
        ldrow(u0+14, pc2, qc2); ldrow(u0+15, pc3, qc3);
    }
    __syncthreads();
    for (int i = lane; i < PER; i += 64) {
        cluster[base + i] = base + clus[i];
        int m = mt[i];
        mate[base + i] = (m < 0) ? -1 : base + m;
    }
}

// K5: single-block inclusive scan of is_rep -> new_id, nc
__global__ __launch_bounds__(1024) void k5_scan(const int* __restrict__ cluster,
                                                int* __restrict__ newid,
                                                int* __restrict__ ncp) {
    __shared__ int wsum[16];
    __shared__ int carry;
    const int tid = threadIdx.x;
    const int lane = tid & 63;
    const int wid = tid >> 6;
    if (tid == 0) carry = 0;
    __syncthreads();
    for (int bse = 0; bse < NN; bse += 1024) {
        int u = bse + tid;
        int v = (u < NN && cluster[u] == u) ? 1 : 0;
        int s = v;
        #pragma unroll
        for (int off = 1; off < 64; off <<= 1) {
            int t = __shfl_up(s, off, 64);
            if (lane >= off) s += t;
        }
        if (lane == 63) wsum[wid] = s;
        __syncthreads();
        if (wid == 0) {
            int w2 = (lane < 16) ? wsum[lane] : 0;
            #pragma unroll
            for (int off = 1; off < 16; off <<= 1) {
                int t = __shfl_up(w2, off, 64);
                if (lane >= off) w2 += t;
            }
            if (lane < 16) wsum[lane] = w2;
        }
        __syncthreads();
        int wpre = (wid > 0) ? wsum[wid - 1] : 0;
        int carryv = carry;
        if (u < NN) newid[u] = carryv + wpre + s - 1;
        int total = wsum[15];
        __syncthreads();
        if (tid == 0) carry = carryv + total;
        __syncthreads();
    }
    if (tid == 0) *ncp = carry;
}

// K6: cluster id map + representative lookup
__global__ void k6_relabel(const int* __restrict__ cluster, const int* __restrict__ newid,
                           int* __restrict__ cmap, int* __restrict__ repof) {
    int u = blockIdx.x * blockDim.x + threadIdx.x;
    if (u >= NN) return;
    int cl = cluster[u];
    int cid = newid[cl];
    cmap[u] = cid;
    if (cl == u) repof[cid] = u;
}

// K7: max-pool features into d_out's [N,H] region + pooled batch vector
__global__ __launch_bounds__(128) void k7_pool(const float* __restrict__ h,
                                               const int* __restrict__ repof,
                                               const int* __restrict__ mate,
                                               const int* __restrict__ batch,
                                               const int* __restrict__ ncp,
                                               float* __restrict__ xout,
                                               float* __restrict__ bpool) {
    int cid = blockIdx.x;
    int tid = threadIdx.x;
    int nc = *ncp;
    if (cid >= nc) {
        #pragma unroll
        for (int q = 0; q < 3; ++q) xout[(size_t)cid * HH + tid + q * 128] = 0.f;
        if (tid == 0) bpool[cid] = 0.f;
        return;
    }
    int u = repof[cid];
    int v = mate[u];
    const float* hu = h + (size_t)u * HH;
    const float* hv = h + (size_t)(v >= 0 ? v : u) * HH;
    #pragma unroll
    for (int q = 0; q < 3; ++q) {
        int j = tid + q * 128;
        float a = hu[j];
        if (v >= 0) a = fmaxf(a, hv[j]);
        xout[(size_t)cid * HH + j] = a;
    }
    if (tid == 0) bpool[cid] = (float)batch[u];
}

// K8: per-destination-cluster candidate source lists (with duplicates)
__global__ void k8_adj(const int* __restrict__ ei, const int* __restrict__ cmap,
                       int* __restrict__ adjcnt, int* __restrict__ adj) {
    int g = blockIdx.x * blockDim.x + threadIdx.x;
    if (g >= EE) return;
    int cs = cmap[ei[g]];
    int cd = cmap[ei[EE + g]];
    if (cs == cd) return;
    int slot = atomicAdd(&adjcnt[cd], 1);
    if (slot < 128) adj[(size_t)cd * 128 + slot] = cs;
}

// K9: dedupe + sum pooled rows -> aggr
__global__ __launch_bounds__(128) void k9_aggr(const int* __restrict__ adjcnt,
                                               const int* __restrict__ adj,
                                               const float* __restrict__ x,
                                               const int* __restrict__ ncp,
                                               float* __restrict__ aggr) {
    int cid = blockIdx.x;
    int tid = threadIdx.x;
    if (cid >= *ncp) return;
    int cnt = adjcnt[cid]; if (cnt > 128) cnt = 128;
    __shared__ int vals[128];
    __shared__ int keep[128];
    if (tid < cnt) vals[tid] = adj[(size_t)cid * 128 + tid];
    __syncthreads();
    if (tid < cnt) {
        int v = vals[tid]; int k = 1;
        for (int m = 0; m < tid; ++m) if (vals[m] == v) { k = 0; break; }
        keep[tid] = k;
    }
    __syncthreads();
    float a0 = 0.f, a1 = 0.f, a2 = 0.f;
    for (int e = 0; e < cnt; ++e) {
        if (keep[e]) {
            const float* xr = x + (size_t)vals[e] * HH;
            a0 += xr[tid]; a1 += xr[tid + 128]; a2 += xr[tid + 256];
        }
    }
    aggr[(size_t)cid * HH + tid]       = a0;
    aggr[(size_t)cid * HH + tid + 128] = a1;
    aggr[(size_t)cid * HH + tid + 256] = a2;
}

// K10: out = relu([aggr | max(h_u,h_v)] @ [Wrel|Wroot]^T + b_rel)
__global__ __launch_bounds__(256) void k10_gemm(const float* __restrict__ aggr,
                                                const float* __restrict__ h,
                                                const int* __restrict__ repof,
                                                const int* __restrict__ mate,
                                                const float* __restrict__ Wrel,
                                                const float* __restrict__ Wroot,
                                                const float* __restrict__ brel,
                                                float* __restrict__ out,
                                                const int* __restrict__ ncp) {
    const int nc = *ncp;
    const int row0 = blockIdx.x * 64;
    const int col0 = blockIdx.y * 64;
    if (row0 >= nc) return;
    __shared__ float As[32][68];
    __shared__ float Ws[32][68];
    __shared__ int us[64], vs[64];
    const int tid = threadIdx.x;
    if (tid < 64) {
        int r = row0 + tid;
        int u = 0, v = -1;
        if (r < nc) { u = repof[r]; v = mate[u]; }
        us[tid] = u; vs[tid] = v;
    }
    __syncthreads();
    float acc[4][4] = {};
    const int ty = tid >> 4, tx = tid & 15;
    for (int kt = 0; kt < 2 * HH; kt += 32) {
        #pragma unroll
        for (int q = 0; q < 2; ++q) {
            int idx = tid + q * 256;
            int r   = idx >> 3;
            int kq  = (idx & 7) << 2;
            int k   = kt + kq;
            int grow = row0 + r;
            bool rv = (grow < nc);
            float4 val;
            if (k < HH) {
                val = *(const float4*)(aggr + (size_t)(rv ? grow : 0) * HH + k);
            } else {
                int kk = k - HH;
                int u = us[r], v = vs[r];
                float4 a = *(const float4*)(h + (size_t)u * HH + kk);
                if (v >= 0) {
                    float4 b = *(const float4*)(h + (size_t)v * HH + kk);
                    a.x = fmaxf(a.x, b.x); a.y = fmaxf(a.y, b.y);
                    a.z = fmaxf(a.z, b.z); a.w = fmaxf(a.w, b.w);
                }
                val = a;
            }
            if (!rv) val = make_float4(0.f, 0.f, 0.f, 0.f);
            As[kq + 0][r] = val.x; As[kq + 1][r] = val.y;
            As[kq + 2][r] = val.z; As[kq + 3][r] = val.w;
        }
        {
            const float* Wsrc = (kt < HH) ? Wrel : Wroot;
            int kk0 = (kt < HH) ? kt : kt - HH;
            #pragma unroll
            for (int q = 0; q < 2; ++q) {
                int idx = tid + q * 256;
                int j   = idx >> 3;
                int kq  = (idx & 7) << 2;
                float4 w = *(const float4*)(Wsrc + (size_t)(col0 + j) * HH + kk0 + kq);
                Ws[kq + 0][j] = w.x; Ws[kq + 1][j] = w.y;
                Ws[kq + 2][j] = w.z; Ws[kq + 3][j] = w.w;
            }
        }
        __syncthreads();
        #pragma unroll
        for (int k = 0; k < 32; ++k) {
            float a[4], w[4];
            #pragma unroll
            for (int i = 0; i < 4; ++i) a[i] = As[k][ty * 4 + i];
            #pragma unroll
            for (int n = 0; n < 4; ++n) w[n] = Ws[k][tx * 4 + n];
            #pragma unroll
            for (int i = 0; i < 4; ++i)
                #pragma unroll
                for (int n = 0; n < 4; ++n)
                    acc[i][n] += a[i] * w[n];
        }
        __syncthreads();
    }
    #pragma unroll
    for (int i = 0; i < 4; ++i) {
        int r = row0 + ty * 4 + i;
        if (r >= nc) continue;
        #pragma unroll
        for (int n = 0; n < 4; ++n) {
            int j = col0 + tx * 4 + n;
            float v = acc[i][n] + brel[j];
            out[(size_t)r * HH + j] = v > 0.f ? v : 0.f;
        }
    }
}

extern "C" void kernel_launch(void* const* d_in, const int* in_sizes, int n_in,
                              void* d_out, int out_size, void* d_ws, size_t ws_size,
                              hipStream_t stream) {
    const float* h     = (const float*)d_in[0];
    const int*   ei    = (const int*)d_in[1];
    const float* ew    = (const float*)d_in[2];
    const int*   batch = (const int*)d_in[3];
    const float* Wrel  = (const float*)d_in[4];
    const float* brel  = (const float*)d_in[5];
    const float* Wroot = (const float*)d_in[6];
    float* out = (float*)d_out;

    unsigned char* w8 = (unsigned char*)d_ws;
    int*   nbrs   = (int*)(w8 + OFF_NBRS);
    float* wts    = (float*)(w8 + OFF_WTS);
    int*   adj    = (int*)(w8 + OFF_ADJ);
    int*   cnt2   = (int*)(w8 + OFF_CNT2);
    int*   adjcnt = (int*)(w8 + OFF_ADJC);
    int*   clus   = (int*)(w8 + OFF_CLUS);
    int*   mate   = (int*)(w8 + OFF_MATE);
    int*   newid  = (int*)(w8 + OFF_NEWID);
    int*   cmap   = (int*)(w8 + OFF_CMAP);
    int*   repof  = (int*)(w8 + OFF_REPOF);
    int*   ncp    = (int*)(w8 + OFF_NC);
    float* aggr   = (float*)(w8 + OFF_AGGR);

    float* xout  = out;
    float* bpool = out + (size_t)NN * HH;

    hipLaunchKernelGGL(k0_init,    dim3((NN + 255) / 256), dim3(256), 0, stream, cnt2, adjcnt);
    hipLaunchKernelGGL(k1_build,   dim3((NN * 64 + 255) / 256), dim3(256), 0, stream, ei, ew, nbrs, wts);
    hipLaunchKernelGGL(k2_scatter, dim3((NKE + 255) / 256), dim3(256), 0, stream, ei, cnt2, nbrs);
    hipLaunchKernelGGL(k3_rank,    dim3((NN * 64 + 255) / 256), dim3(256), 0, stream, cnt2, ew, nbrs, wts);
    hipLaunchKernelGGL(k4_graclus, dim3(8), dim3(64), 0, stream, nbrs, wts, clus, mate);
    hipLaunchKernelGGL(k5_scan,    dim3(1), dim3(1024), 0, stream, clus, newid, ncp);
    hipLaunchKernelGGL(k6_relabel, dim3((NN + 255) / 256), dim3(256), 0, stream, clus, newid, cmap, repof);
    hipLaunchKernelGGL(k7_pool,    dim3(NN), dim3(128), 0, stream, h, repof, mate, batch, ncp, xout, bpool);
    hipLaunchKernelGGL(k8_adj,     dim3((EE + 255) / 256), dim3(256), 0, stream, ei, cmap, adjcnt, adj);
    hipLaunchKernelGGL(k9_aggr,    dim3(NN), dim3(128), 0, stream, adjcnt, adj, xout, ncp, aggr);
    hipLaunchKernelGGL(k10_gemm,   dim3((NN + 63) / 64, HH / 64), dim3(256), 0, stream,
                       aggr, h, repof, mate, Wrel, Wroot, brel, out, ncp);
}